// Round 3
// baseline (260.655 us; speedup 1.0000x reference)
//
#include <hip/hip_runtime.h>

// Problem constants (match reference)
constexpr int B = 1024, N = 100, C = 256, K = 3;
constexpr int ROWS = B * N;                 // 102400
constexpr int ROWS_PER_WAVE = 4;
constexpr int WAVES_PER_BLOCK = 4;          // 256 threads
constexpr int ROWS_PER_BLOCK = ROWS_PER_WAVE * WAVES_PER_BLOCK;  // 16
constexpr int BLOCKS = ROWS / ROWS_PER_BLOCK;                    // 6400, exact
constexpr float LN_EPS = 1e-5f;

// Native clang vector type — accepted by __builtin_nontemporal_store
// (HIP's float4 is a class and is rejected).
typedef float nfloat4 __attribute__((ext_vector_type(4)));

__global__ __launch_bounds__(256) void dydwconv_ln_kernel(
    const float* __restrict__ query,   // [B,N,C]
    const float* __restrict__ value,   // [B,N,C]
    const float* __restrict__ Ww,      // [K,C]
    const float* __restrict__ bw,      // [K]
    const float* __restrict__ gamma,   // [C]
    const float* __restrict__ beta,    // [C]
    float* __restrict__ out)           // [B,N,C]
{
    __shared__ float sW[K * C];        // 3 KB
    __shared__ float sGamma[C];
    __shared__ float sBeta[C];

    const int t = threadIdx.x;
    sW[t]         = Ww[t];
    sW[t + C]     = Ww[t + C];
    sW[t + 2 * C] = Ww[t + 2 * C];
    sGamma[t] = gamma[t];
    sBeta[t]  = beta[t];
    __syncthreads();

    const int wave = t >> 6;
    const int lane = t & 63;
    const int c0   = lane * 4;
    const int row0 = (blockIdx.x * WAVES_PER_BLOCK + wave) * ROWS_PER_WAVE;

    // Issue all 8 global loads up front (independent -> 8 outstanding vmem ops)
    float4 q[ROWS_PER_WAVE], v[ROWS_PER_WAVE];
    #pragma unroll
    for (int r = 0; r < ROWS_PER_WAVE; ++r) {
        const size_t base = (size_t)(row0 + r) * C + c0;
        q[r] = *(const float4*)(query + base);
        v[r] = *(const float4*)(value + base);
    }

    // Dynamic-kernel partial dots: 12 independent reduction chains
    const float W0a = sW[c0],       W0b = sW[c0+1],       W0c = sW[c0+2],       W0d = sW[c0+3];
    const float W1a = sW[C+c0],     W1b = sW[C+c0+1],     W1c = sW[C+c0+2],     W1d = sW[C+c0+3];
    const float W2a = sW[2*C+c0],   W2b = sW[2*C+c0+1],   W2c = sW[2*C+c0+2],   W2d = sW[2*C+c0+3];

    float p[ROWS_PER_WAVE][K];
    #pragma unroll
    for (int r = 0; r < ROWS_PER_WAVE; ++r) {
        p[r][0] = q[r].x * W0a + q[r].y * W0b + q[r].z * W0c + q[r].w * W0d;
        p[r][1] = q[r].x * W1a + q[r].y * W1b + q[r].z * W1c + q[r].w * W1d;
        p[r][2] = q[r].x * W2a + q[r].y * W2b + q[r].z * W2c + q[r].w * W2d;
    }
    #pragma unroll
    for (int off = 32; off > 0; off >>= 1) {
        #pragma unroll
        for (int r = 0; r < ROWS_PER_WAVE; ++r) {
            p[r][0] += __shfl_xor(p[r][0], off);
            p[r][1] += __shfl_xor(p[r][1], off);
            p[r][2] += __shfl_xor(p[r][2], off);
        }
    }
    const float bw0 = bw[0], bw1 = bw[1], bw2 = bw[2];  // uniform scalar loads

    // Conv halo + depthwise K=3 conv + LN stats (per-row)
    float o[ROWS_PER_WAVE][4];
    float s[ROWS_PER_WAVE], ss[ROWS_PER_WAVE];
    #pragma unroll
    for (int r = 0; r < ROWS_PER_WAVE; ++r) {
        const float w0 = p[r][0] + bw0;
        const float w1 = p[r][1] + bw1;
        const float w2 = p[r][2] + bw2;
        float vl = __shfl_up(v[r].w, 1);
        float vr = __shfl_down(v[r].x, 1);
        if (lane == 0)  vl = 0.0f;
        if (lane == 63) vr = 0.0f;
        o[r][0] = vl     * w0 + v[r].x * w1 + v[r].y * w2;
        o[r][1] = v[r].x * w0 + v[r].y * w1 + v[r].z * w2;
        o[r][2] = v[r].y * w0 + v[r].z * w1 + v[r].w * w2;
        o[r][3] = v[r].z * w0 + v[r].w * w1 + vr     * w2;
        s[r]  = o[r][0] + o[r][1] + o[r][2] + o[r][3];
        ss[r] = o[r][0]*o[r][0] + o[r][1]*o[r][1] + o[r][2]*o[r][2] + o[r][3]*o[r][3];
    }
    // 8 interleaved LN reduction chains
    #pragma unroll
    for (int off = 32; off > 0; off >>= 1) {
        #pragma unroll
        for (int r = 0; r < ROWS_PER_WAVE; ++r) {
            s[r]  += __shfl_xor(s[r],  off);
            ss[r] += __shfl_xor(ss[r], off);
        }
    }

    const float g0 = sGamma[c0], g1 = sGamma[c0+1], g2 = sGamma[c0+2], g3 = sGamma[c0+3];
    const float be0 = sBeta[c0], be1 = sBeta[c0+1], be2 = sBeta[c0+2], be3 = sBeta[c0+3];

    #pragma unroll
    for (int r = 0; r < ROWS_PER_WAVE; ++r) {
        const float mu  = s[r] * (1.0f / C);
        const float var = ss[r] * (1.0f / C) - mu * mu;
        const float inv = rsqrtf(var + LN_EPS);
        nfloat4 res;
        res.x = (o[r][0] - mu) * inv * g0 + be0;
        res.y = (o[r][1] - mu) * inv * g1 + be1;
        res.z = (o[r][2] - mu) * inv * g2 + be2;
        res.w = (o[r][3] - mu) * inv * g3 + be3;
        const size_t base = (size_t)(row0 + r) * C + c0;
        // Non-temporal store: output is write-once, keep it out of L2/LLC
        __builtin_nontemporal_store(res, (nfloat4*)(out + base));
    }
}

extern "C" void kernel_launch(void* const* d_in, const int* in_sizes, int n_in,
                              void* d_out, int out_size, void* d_ws, size_t ws_size,
                              hipStream_t stream) {
    const float* query = (const float*)d_in[0];
    const float* value = (const float*)d_in[1];
    const float* Ww    = (const float*)d_in[2];
    const float* bw    = (const float*)d_in[3];
    const float* gamma = (const float*)d_in[4];
    const float* beta  = (const float*)d_in[5];
    float* out = (float*)d_out;

    dydwconv_ln_kernel<<<BLOCKS, 256, 0, stream>>>(query, value, Ww, bw, gamma, beta, out);
}